// Round 17
// baseline (29.876 us; speedup 1.0000x reference)
//
#include <hip/hip_runtime.h>

#define Bb 128
#define Ww 128
#define Nn 512
#define ALPHA 0.2f
#define LOG2E 1.44269504088896340736f

typedef __attribute__((ext_vector_type(8))) short short8;
typedef __attribute__((ext_vector_type(4))) float f32x4;

// v_cvt_pk_bf16_f32: packs (lo,hi) -> u32 of 2 bf16 (RNE; proven R9-R14)
__device__ __forceinline__ unsigned pk_bf16(float lo, float hi) {
  unsigned r;
  asm("v_cvt_pk_bf16_f32 %0, %1, %2" : "=v"(r) : "v"(lo), "v"(hi));
  return r;
}

// v_exp_f32 computes 2^x on gfx950 (proven R13/R14)
__device__ __forceinline__ float v_exp2(float x) {
  float r;
  asm("v_exp_f32 %0, %1" : "=v"(r) : "v"(x));
  return r;
}

// ---- dynamic LDS layout (bytes) ---- (R13 verbatim)
#define T_OFF   0
#define T_BYTES (64 * 129 * 8 * 2)     // ushort tile[64 jg][129 w][8] = 132096
#define SR_OFF  (T_OFF + T_BYTES)      // float sred[512*8] = 16384
#define S1_OFF  (SR_OFF + 16384)       // float s1s[512]    = 2048
#define S2_OFF  (S1_OFF + 2048)        // float s2s[512]    = 2048
#define CV_OFF  (S2_OFF + 2048)        // float cvs[129]    (pad 528)
#define SMEM10  (CV_OFF + 528)         // 153104 < 160 KiB

// One block = (batch b, i-half). 512 threads = 8 waves, 1 block/CU.
// R13 structure + numerics exactly; ONLY change: Wfc preloaded to registers
// BEFORE the x loads are issued, so P0's cvec waits at vmcnt(32) (x in flight)
// instead of running after the x stream (counted-vmcnt overlap, T4 pattern).
__launch_bounds__(512, 1)
__global__ void attn_f8(const float* __restrict__ x, const float* __restrict__ Wfc,
                        const float* __restrict__ bfc, const float* __restrict__ attn,
                        float* __restrict__ out) {
  extern __shared__ char smem[];
  ushort* tile = (ushort*)(smem + T_OFF);
  float*  sred = (float*)(smem + SR_OFF);
  float*  s1s  = (float*)(smem + S1_OFF);
  float*  s2s  = (float*)(smem + S2_OFF);
  float*  cvs  = (float*)(smem + CV_OFF);

  const int bid = blockIdx.x;
  const int xcd = bid & 7, idx = bid >> 3;
  const int b  = xcd * 16 + (idx >> 1);      // sibling i-half blocks share an XCD/L2
  const int i0 = (idx & 1) * 256;
  const int t  = threadIdx.x;
  const int wv = t >> 6, lane = t & 63;
  const int wl = lane & 15, lg = lane >> 4;
  const float* xb = x + (size_t)b * (Ww * Nn);
  const int q = t & 63;

  // ---- P-1a: issue Wfc loads FIRST (oldest in VMEM queue) ----
  const int wcol = t & 127, vq = t >> 7;
  float wreg[32];
#pragma unroll
  for (int vi = 0; vi < 32; ++vi)
    wreg[vi] = Wfc[(size_t)(vq * 32 + vi) * Ww + wcol];
  __builtin_amdgcn_sched_barrier(0);   // pin: Wfc issue before x issue

  // ---- P-1b: issue ALL 32 x float4 loads (younger; retire after Wfc) ----
  float4 L0[16], L1[16];
#pragma unroll
  for (int k = 0; k < 16; ++k) {
    const float* s = xb + (size_t)(wv + 8 * k) * Nn + 8 * q;
    L0[k] = *reinterpret_cast<const float4*>(s);
    L1[k] = *reinterpret_cast<const float4*>(s + 4);
  }
  __builtin_amdgcn_sched_barrier(0);   // pin: x issue before P0 consumes wreg

  // ---- P0: cvec from wreg — waits only for Wfc (vmcnt(32)), x stays in flight ----
  {
    float p = 0.f;
#pragma unroll
    for (int vi = 0; vi < 32; ++vi)
      p = fmaf(attn[Ww + vq * 32 + vi], wreg[vi], p);
    sred[t] = p;
    if (t < 64) {
      float c0p = fmaf(bfc[t], attn[Ww + t], bfc[t + 64] * attn[Ww + 64 + t]);
#pragma unroll
      for (int off = 32; off; off >>= 1) c0p += __shfl_xor(c0p, off);
      if (t == 0) cvs[Ww] = c0p;
    }
  }
  __syncthreads();
  if (t < Ww) cvs[t] = sred[t] + sred[t + 128] + sred[t + 256] + sred[t + 384];
  __syncthreads();

  // ---- P1: drain/process the 32 in-flight x loads (R13 verbatim) ----
  float s1p[8] = {0, 0, 0, 0, 0, 0, 0, 0};
  float s2p[8] = {0, 0, 0, 0, 0, 0, 0, 0};
#pragma unroll
  for (int k = 0; k < 16; ++k) {
    const int w = wv + 8 * k;
    const float aw = attn[w];
    const float cw = cvs[w];
    const float4 lo = L0[k], hi = L1[k];
    s1p[0] = fmaf(lo.x, aw, s1p[0]); s1p[1] = fmaf(lo.y, aw, s1p[1]);
    s1p[2] = fmaf(lo.z, aw, s1p[2]); s1p[3] = fmaf(lo.w, aw, s1p[3]);
    s1p[4] = fmaf(hi.x, aw, s1p[4]); s1p[5] = fmaf(hi.y, aw, s1p[5]);
    s1p[6] = fmaf(hi.z, aw, s1p[6]); s1p[7] = fmaf(hi.w, aw, s1p[7]);
    s2p[0] = fmaf(lo.x, cw, s2p[0]); s2p[1] = fmaf(lo.y, cw, s2p[1]);
    s2p[2] = fmaf(lo.z, cw, s2p[2]); s2p[3] = fmaf(lo.w, cw, s2p[3]);
    s2p[4] = fmaf(hi.x, cw, s2p[4]); s2p[5] = fmaf(hi.y, cw, s2p[5]);
    s2p[6] = fmaf(hi.z, cw, s2p[6]); s2p[7] = fmaf(hi.w, cw, s2p[7]);
    uint4 pk;
    pk.x = pk_bf16(lo.x, lo.y); pk.y = pk_bf16(lo.z, lo.w);
    pk.z = pk_bf16(hi.x, hi.y); pk.w = pk_bf16(hi.z, hi.w);
    *reinterpret_cast<uint4*>(tile + ((size_t)q * 129 + w) * 8) = pk;  // conflict-free
  }

  // ---- P2: reduce s1/s2 across the 8 w-groups; scale by log2(e) ----
  {
    f32x4* sv = reinterpret_cast<f32x4*>(&sred[t * 8]);
    sv[0] = (f32x4){s1p[0], s1p[1], s1p[2], s1p[3]};
    sv[1] = (f32x4){s1p[4], s1p[5], s1p[6], s1p[7]};
  }
  __syncthreads();
  float red;
  {
    float a = 0.f;
#pragma unroll
    for (int g = 0; g < 8; ++g) a += sred[((g * 64) + (t >> 3)) * 8 + (t & 7)];
    red = a;
  }
  __syncthreads();   // all sred reads done before rewrite
  {
    s1s[t] = red * LOG2E;
    f32x4* sv = reinterpret_cast<f32x4*>(&sred[t * 8]);
    sv[0] = (f32x4){s2p[0], s2p[1], s2p[2], s2p[3]};
    sv[1] = (f32x4){s2p[4], s2p[5], s2p[6], s2p[7]};
  }
  __syncthreads();
  {
    float d = 0.f;
#pragma unroll
    for (int g = 0; g < 8; ++g) d += sred[((g * 64) + (t >> 3)) * 8 + (t & 7)];
    s2s[t] = (d + cvs[Ww]) * LOG2E;
  }
  __syncthreads();

  // ---- P4: MFMA loop; no max subtraction; exp2; denominators via MFMA x ones ----
  float s1i[2];
  s1i[0] = s1s[i0 + wv * 32 + wl];
  s1i[1] = s1s[i0 + wv * 32 + 16 + wl];

  f32x4 acc[2][8];
  f32x4 accl[2];
#pragma unroll
  for (int a = 0; a < 2; ++a) {
    accl[a] = (f32x4){0.f, 0.f, 0.f, 0.f};
#pragma unroll
    for (int f = 0; f < 8; ++f) acc[a][f] = (f32x4){0.f, 0.f, 0.f, 0.f};
  }
  short8 ones;
#pragma unroll
  for (int e = 0; e < 8; ++e) ones[e] = (short)0x3F80;  // bf16 1.0

  for (int jj = 0; jj < 16; ++jj) {
    const int jb = jj * 32 + 8 * lg;  // this lane's 8 consecutive j's
    float sv[8];
    *reinterpret_cast<float4*>(&sv[0]) = *reinterpret_cast<const float4*>(&s2s[jb]);
    *reinterpret_cast<float4*>(&sv[4]) = *reinterpret_cast<const float4*>(&s2s[jb + 4]);
    float p0[8], p1[8];
#pragma unroll
    for (int e = 0; e < 8; ++e) {
      const float u0 = s1i[0] + sv[e];
      p0[e] = v_exp2(fmaxf(u0, ALPHA * u0));   // |u| <~ 16 pre-scaled -> safe
      const float u1 = s1i[1] + sv[e];
      p1[e] = v_exp2(fmaxf(u1, ALPHA * u1));
    }
    short8 af0, af1;
    unsigned* a0u = reinterpret_cast<unsigned*>(&af0);
    unsigned* a1u = reinterpret_cast<unsigned*>(&af1);
    a0u[0] = pk_bf16(p0[0], p0[1]); a0u[1] = pk_bf16(p0[2], p0[3]);
    a0u[2] = pk_bf16(p0[4], p0[5]); a0u[3] = pk_bf16(p0[6], p0[7]);
    a1u[0] = pk_bf16(p1[0], p1[1]); a1u[1] = pk_bf16(p1[2], p1[3]);
    a1u[2] = pk_bf16(p1[4], p1[5]); a1u[3] = pk_bf16(p1[6], p1[7]);

    const ushort* tb = tile + (size_t)(jj * 4 + lg) * 129 * 8;
#pragma unroll
    for (int f = 0; f < 8; ++f) {
      const short8 bfr = *reinterpret_cast<const short8*>(tb + (16 * f + wl) * 8);
      acc[0][f] = __builtin_amdgcn_mfma_f32_16x16x32_bf16(af0, bfr, acc[0][f], 0, 0, 0);
      acc[1][f] = __builtin_amdgcn_mfma_f32_16x16x32_bf16(af1, bfr, acc[1][f], 0, 0, 0);
    }
    accl[0] = __builtin_amdgcn_mfma_f32_16x16x32_bf16(af0, ones, accl[0], 0, 0, 0);
    accl[1] = __builtin_amdgcn_mfma_f32_16x16x32_bf16(af1, ones, accl[1], 0, 0, 0);
  }

  // ---- P6: epilogue — sigmoid via exp2 (log2e folded into invl) ----
  float* outb = out + (size_t)b * (Ww * Nn);
#pragma unroll
  for (int a = 0; a < 2; ++a) {
    float invl[4];
#pragma unroll
    for (int m = 0; m < 4; ++m) invl[m] = LOG2E / accl[a][m];
    const int ibase = i0 + wv * 32 + 16 * a + lg * 4;
#pragma unroll
    for (int f = 0; f < 8; ++f) {
      float4 o;
      o.x = 1.f / (1.f + v_exp2(-(acc[a][f][0] * invl[0])));
      o.y = 1.f / (1.f + v_exp2(-(acc[a][f][1] * invl[1])));
      o.z = 1.f / (1.f + v_exp2(-(acc[a][f][2] * invl[2])));
      o.w = 1.f / (1.f + v_exp2(-(acc[a][f][3] * invl[3])));
      *reinterpret_cast<float4*>(outb + (16 * f + wl) * Nn + ibase) = o;
    }
  }
}

extern "C" void kernel_launch(void* const* d_in, const int* in_sizes, int n_in,
                              void* d_out, int out_size, void* d_ws, size_t ws_size,
                              hipStream_t stream) {
  const float* x    = (const float*)d_in[0];  // (128,128,512)
  const float* Wfc  = (const float*)d_in[1];  // (128,128)
  const float* bfc  = (const float*)d_in[2];  // (128,)
  const float* attn = (const float*)d_in[3];  // (256,1)
  float* out = (float*)d_out;                 // (128,128,512)

  (void)hipFuncSetAttribute(reinterpret_cast<const void*>(&attn_f8),
                            hipFuncAttributeMaxDynamicSharedMemorySize, SMEM10);
  attn_f8<<<256, 512, SMEM10, stream>>>(x, Wfc, bfc, attn, out);
}

// Round 18
// 28.072 us; speedup vs baseline: 1.0642x; 1.0642x over previous
//
#include <hip/hip_runtime.h>

#define Bb 128
#define Ww 128
#define Nn 512
#define ALPHA 0.2f
#define LOG2E 1.44269504088896340736f

typedef __attribute__((ext_vector_type(8))) short short8;
typedef __attribute__((ext_vector_type(4))) float f32x4;

// v_cvt_pk_bf16_f32: packs (lo,hi) -> u32 of 2 bf16 (RNE; proven R9-R17)
__device__ __forceinline__ unsigned pk_bf16(float lo, float hi) {
  unsigned r;
  asm("v_cvt_pk_bf16_f32 %0, %1, %2" : "=v"(r) : "v"(lo), "v"(hi));
  return r;
}

// v_exp_f32 computes 2^x on gfx950 (proven R13/R14/R17)
__device__ __forceinline__ float v_exp2(float x) {
  float r;
  asm("v_exp_f32 %0, %1" : "=v"(r) : "v"(x));
  return r;
}

// v_rcp_f32: ~1ulp reciprocal, 1 instruction (vs ~9-inst IEEE div sequence)
__device__ __forceinline__ float v_rcp(float x) {
  float r;
  asm("v_rcp_f32 %0, %1" : "=v"(r) : "v"(x));
  return r;
}

// ---- dynamic LDS layout (bytes) ---- (R13 verbatim)
#define T_OFF   0
#define T_BYTES (64 * 129 * 8 * 2)     // ushort tile[64 jg][129 w][8] = 132096
#define SR_OFF  (T_OFF + T_BYTES)      // float sred[512*8] = 16384
#define S1_OFF  (SR_OFF + 16384)       // float s1s[512]    = 2048
#define S2_OFF  (S1_OFF + 2048)        // float s2s[512]    = 2048
#define CV_OFF  (S2_OFF + 2048)        // float cvs[129]    (pad 528)
#define SMEM11  (CV_OFF + 528)         // 153104 < 160 KiB

// One block = (batch b, i-half). 512 threads = 8 waves, 1 block/CU.
// R13 structure + numerics exactly; ONLY change: v_rcp replaces IEEE division
// in the epilogue (invl and sigmoid).
__launch_bounds__(512, 1)
__global__ void attn_f9(const float* __restrict__ x, const float* __restrict__ Wfc,
                        const float* __restrict__ bfc, const float* __restrict__ attn,
                        float* __restrict__ out) {
  extern __shared__ char smem[];
  ushort* tile = (ushort*)(smem + T_OFF);
  float*  sred = (float*)(smem + SR_OFF);
  float*  s1s  = (float*)(smem + S1_OFF);
  float*  s2s  = (float*)(smem + S2_OFF);
  float*  cvs  = (float*)(smem + CV_OFF);

  const int bid = blockIdx.x;
  const int xcd = bid & 7, idx = bid >> 3;
  const int b  = xcd * 16 + (idx >> 1);      // sibling i-half blocks share an XCD/L2
  const int i0 = (idx & 1) * 256;
  const int t  = threadIdx.x;
  const int wv = t >> 6, lane = t & 63;
  const int wl = lane & 15, lg = lane >> 4;
  const float* xb = x + (size_t)b * (Ww * Nn);
  const int q = t & 63;

  // ---- P0: cvec[w] = sum_v a2[v]*Wfc[v][w] (512 threads), c0 = b_fc . a2 ----
  {
    const int wcol = t & 127, vq = t >> 7;
    float p = 0.f;
#pragma unroll 8
    for (int vi = 0; vi < 32; ++vi) {
      const int v = vq * 32 + vi;
      p = fmaf(attn[Ww + v], Wfc[v * Ww + wcol], p);
    }
    sred[t] = p;
    if (t < 64) {
      float c0p = fmaf(bfc[t], attn[Ww + t], bfc[t + 64] * attn[Ww + 64 + t]);
#pragma unroll
      for (int off = 32; off; off >>= 1) c0p += __shfl_xor(c0p, off);
      if (t == 0) cvs[Ww] = c0p;
    }
  }
  __syncthreads();
  if (t < Ww) cvs[t] = sred[t] + sred[t + 128] + sred[t + 256] + sred[t + 384];
  __syncthreads();

  // ---- P1: stream x[b]; ALL 32 float4 loads issued upfront, then process ----
  // Thread (wv, q): rows w = wv + 8k, n-slice [8q, 8q+8).
  float s1p[8] = {0, 0, 0, 0, 0, 0, 0, 0};
  float s2p[8] = {0, 0, 0, 0, 0, 0, 0, 0};
  {
    float4 L0[16], L1[16];
#pragma unroll
    for (int k = 0; k < 16; ++k) {  // issue phase: 32 loads in flight
      const float* s = xb + (size_t)(wv + 8 * k) * Nn + 8 * q;
      L0[k] = *reinterpret_cast<const float4*>(s);
      L1[k] = *reinterpret_cast<const float4*>(s + 4);
    }
#pragma unroll
    for (int k = 0; k < 16; ++k) {  // drain phase: vmcnt waits overlap younger loads
      const int w = wv + 8 * k;
      const float aw = attn[w];
      const float cw = cvs[w];
      const float4 lo = L0[k], hi = L1[k];
      s1p[0] = fmaf(lo.x, aw, s1p[0]); s1p[1] = fmaf(lo.y, aw, s1p[1]);
      s1p[2] = fmaf(lo.z, aw, s1p[2]); s1p[3] = fmaf(lo.w, aw, s1p[3]);
      s1p[4] = fmaf(hi.x, aw, s1p[4]); s1p[5] = fmaf(hi.y, aw, s1p[5]);
      s1p[6] = fmaf(hi.z, aw, s1p[6]); s1p[7] = fmaf(hi.w, aw, s1p[7]);
      s2p[0] = fmaf(lo.x, cw, s2p[0]); s2p[1] = fmaf(lo.y, cw, s2p[1]);
      s2p[2] = fmaf(lo.z, cw, s2p[2]); s2p[3] = fmaf(lo.w, cw, s2p[3]);
      s2p[4] = fmaf(hi.x, cw, s2p[4]); s2p[5] = fmaf(hi.y, cw, s2p[5]);
      s2p[6] = fmaf(hi.z, cw, s2p[6]); s2p[7] = fmaf(hi.w, cw, s2p[7]);
      uint4 pk;
      pk.x = pk_bf16(lo.x, lo.y); pk.y = pk_bf16(lo.z, lo.w);
      pk.z = pk_bf16(hi.x, hi.y); pk.w = pk_bf16(hi.z, hi.w);
      *reinterpret_cast<uint4*>(tile + ((size_t)q * 129 + w) * 8) = pk;  // conflict-free
    }
  }

  // ---- P2: reduce s1/s2 across the 8 w-groups; scale by log2(e) ----
  {
    f32x4* sv = reinterpret_cast<f32x4*>(&sred[t * 8]);
    sv[0] = (f32x4){s1p[0], s1p[1], s1p[2], s1p[3]};
    sv[1] = (f32x4){s1p[4], s1p[5], s1p[6], s1p[7]};
  }
  __syncthreads();
  float red;
  {
    float a = 0.f;
#pragma unroll
    for (int g = 0; g < 8; ++g) a += sred[((g * 64) + (t >> 3)) * 8 + (t & 7)];
    red = a;
  }
  __syncthreads();   // all sred reads done before rewrite
  {
    s1s[t] = red * LOG2E;
    f32x4* sv = reinterpret_cast<f32x4*>(&sred[t * 8]);
    sv[0] = (f32x4){s2p[0], s2p[1], s2p[2], s2p[3]};
    sv[1] = (f32x4){s2p[4], s2p[5], s2p[6], s2p[7]};
  }
  __syncthreads();
  {
    float d = 0.f;
#pragma unroll
    for (int g = 0; g < 8; ++g) d += sred[((g * 64) + (t >> 3)) * 8 + (t & 7)];
    s2s[t] = (d + cvs[Ww]) * LOG2E;
  }
  __syncthreads();

  // ---- P4: MFMA loop; no max subtraction; exp2; denominators via MFMA x ones ----
  float s1i[2];
  s1i[0] = s1s[i0 + wv * 32 + wl];
  s1i[1] = s1s[i0 + wv * 32 + 16 + wl];

  f32x4 acc[2][8];
  f32x4 accl[2];
#pragma unroll
  for (int a = 0; a < 2; ++a) {
    accl[a] = (f32x4){0.f, 0.f, 0.f, 0.f};
#pragma unroll
    for (int f = 0; f < 8; ++f) acc[a][f] = (f32x4){0.f, 0.f, 0.f, 0.f};
  }
  short8 ones;
#pragma unroll
  for (int e = 0; e < 8; ++e) ones[e] = (short)0x3F80;  // bf16 1.0

  for (int jj = 0; jj < 16; ++jj) {
    const int jb = jj * 32 + 8 * lg;  // this lane's 8 consecutive j's
    float sv[8];
    *reinterpret_cast<float4*>(&sv[0]) = *reinterpret_cast<const float4*>(&s2s[jb]);
    *reinterpret_cast<float4*>(&sv[4]) = *reinterpret_cast<const float4*>(&s2s[jb + 4]);
    float p0[8], p1[8];
#pragma unroll
    for (int e = 0; e < 8; ++e) {
      const float u0 = s1i[0] + sv[e];
      p0[e] = v_exp2(fmaxf(u0, ALPHA * u0));   // |u| <~ 16 pre-scaled -> safe
      const float u1 = s1i[1] + sv[e];
      p1[e] = v_exp2(fmaxf(u1, ALPHA * u1));
    }
    short8 af0, af1;
    unsigned* a0u = reinterpret_cast<unsigned*>(&af0);
    unsigned* a1u = reinterpret_cast<unsigned*>(&af1);
    a0u[0] = pk_bf16(p0[0], p0[1]); a0u[1] = pk_bf16(p0[2], p0[3]);
    a0u[2] = pk_bf16(p0[4], p0[5]); a0u[3] = pk_bf16(p0[6], p0[7]);
    a1u[0] = pk_bf16(p1[0], p1[1]); a1u[1] = pk_bf16(p1[2], p1[3]);
    a1u[2] = pk_bf16(p1[4], p1[5]); a1u[3] = pk_bf16(p1[6], p1[7]);

    const ushort* tb = tile + (size_t)(jj * 4 + lg) * 129 * 8;
#pragma unroll
    for (int f = 0; f < 8; ++f) {
      const short8 bfr = *reinterpret_cast<const short8*>(tb + (16 * f + wl) * 8);
      acc[0][f] = __builtin_amdgcn_mfma_f32_16x16x32_bf16(af0, bfr, acc[0][f], 0, 0, 0);
      acc[1][f] = __builtin_amdgcn_mfma_f32_16x16x32_bf16(af1, bfr, acc[1][f], 0, 0, 0);
    }
    accl[0] = __builtin_amdgcn_mfma_f32_16x16x32_bf16(af0, ones, accl[0], 0, 0, 0);
    accl[1] = __builtin_amdgcn_mfma_f32_16x16x32_bf16(af1, ones, accl[1], 0, 0, 0);
  }

  // ---- P6: epilogue — sigmoid via exp2 + v_rcp (no IEEE division sequences) ----
  float* outb = out + (size_t)b * (Ww * Nn);
#pragma unroll
  for (int a = 0; a < 2; ++a) {
    float invl[4];
#pragma unroll
    for (int m = 0; m < 4; ++m) invl[m] = LOG2E * v_rcp(accl[a][m]);
    const int ibase = i0 + wv * 32 + 16 * a + lg * 4;
#pragma unroll
    for (int f = 0; f < 8; ++f) {
      float4 o;
      o.x = v_rcp(1.f + v_exp2(-(acc[a][f][0] * invl[0])));
      o.y = v_rcp(1.f + v_exp2(-(acc[a][f][1] * invl[1])));
      o.z = v_rcp(1.f + v_exp2(-(acc[a][f][2] * invl[2])));
      o.w = v_rcp(1.f + v_exp2(-(acc[a][f][3] * invl[3])));
      *reinterpret_cast<float4*>(outb + (16 * f + wl) * Nn + ibase) = o;
    }
  }
}

extern "C" void kernel_launch(void* const* d_in, const int* in_sizes, int n_in,
                              void* d_out, int out_size, void* d_ws, size_t ws_size,
                              hipStream_t stream) {
  const float* x    = (const float*)d_in[0];  // (128,128,512)
  const float* Wfc  = (const float*)d_in[1];  // (128,128)
  const float* bfc  = (const float*)d_in[2];  // (128,)
  const float* attn = (const float*)d_in[3];  // (256,1)
  float* out = (float*)d_out;                 // (128,128,512)

  (void)hipFuncSetAttribute(reinterpret_cast<const void*>(&attn_f9),
                            hipFuncAttributeMaxDynamicSharedMemorySize, SMEM11);
  attn_f9<<<256, 512, SMEM11, stream>>>(x, Wfc, bfc, attn, out);
}

// Round 19
// 26.377 us; speedup vs baseline: 1.1326x; 1.0643x over previous
//
#include <hip/hip_runtime.h>

#define Bb 128
#define Ww 128
#define Nn 512
#define ALPHA 0.2f
#define LOG2E 1.44269504088896340736f

typedef __attribute__((ext_vector_type(8))) short short8;
typedef __attribute__((ext_vector_type(4))) float f32x4;

// v_cvt_pk_bf16_f32: packs (lo,hi) -> u32 of 2 bf16 (RNE; proven R9-R18)
__device__ __forceinline__ unsigned pk_bf16(float lo, float hi) {
  unsigned r;
  asm("v_cvt_pk_bf16_f32 %0, %1, %2" : "=v"(r) : "v"(lo), "v"(hi));
  return r;
}

// v_exp_f32 computes 2^x on gfx950 (proven R13-R18)
__device__ __forceinline__ float v_exp2(float x) {
  float r;
  asm("v_exp_f32 %0, %1" : "=v"(r) : "v"(x));
  return r;
}

// v_rcp_f32: ~1ulp reciprocal (proven R18)
__device__ __forceinline__ float v_rcp(float x) {
  float r;
  asm("v_rcp_f32 %0, %1" : "=v"(r) : "v"(x));
  return r;
}

// ---- dynamic LDS layout (bytes) ---- (same as R13/R18)
#define T_OFF   0
#define T_BYTES (64 * 129 * 8 * 2)     // ushort tile[64 jg][129 w][8] = 132096
#define SR_OFF  (T_OFF + T_BYTES)      // float sred[4096] = 16384
#define S1_OFF  (SR_OFF + 16384)       // float s1s[512]   = 2048
#define S2_OFF  (S1_OFF + 2048)        // float s2s[512]   = 2048
#define CV_OFF  (S2_OFF + 2048)        // float cvs[129]   (pad 528)
#define SMEM12  (CV_OFF + 528)         // 153104 < 160 KiB

// One block = (batch b, i-half). 1024 threads = 16 waves = 4 waves/SIMD,
// 1 block/CU. R18's phases re-mapped: per-thread work halves, wave count
// doubles -> 2x latency hiding in every phase. Numerics identical to R18.
__launch_bounds__(1024, 1)
__global__ void attn_k(const float* __restrict__ x, const float* __restrict__ Wfc,
                       const float* __restrict__ bfc, const float* __restrict__ attn,
                       float* __restrict__ out) {
  extern __shared__ char smem[];
  ushort* tile = (ushort*)(smem + T_OFF);
  float*  sred = (float*)(smem + SR_OFF);
  float*  s1s  = (float*)(smem + S1_OFF);
  float*  s2s  = (float*)(smem + S2_OFF);
  float*  cvs  = (float*)(smem + CV_OFF);

  const int bid = blockIdx.x;
  const int xcd = bid & 7, idx = bid >> 3;
  const int b  = xcd * 16 + (idx >> 1);      // sibling i-half blocks share an XCD/L2
  const int i0 = (idx & 1) * 256;
  const int t  = threadIdx.x;                // 0..1023
  const int wvw = t >> 6;                    // wave 0..15
  const int lane = t & 63;
  const int wl = lane & 15, lg = lane >> 4;
  const int g  = t >> 7;                     // stream row-group 0..7
  const int q2 = t & 127;                    // col-slice (4 floats)
  const float* xb = x + (size_t)b * (Ww * Nn);

  // ---- P0: cvec[w] = sum_v a2[v]*Wfc[v][w] (1024 thr, 16 v each); c0 ----
  {
    const int wcol = t & 127, vq = t >> 7;
    float p = 0.f;
#pragma unroll
    for (int vi = 0; vi < 16; ++vi) {
      const int v = vq * 16 + vi;
      p = fmaf(attn[Ww + v], Wfc[v * Ww + wcol], p);
    }
    sred[t] = p;                 // partial for wcol from group vq at sred[vq*128+wcol]
    if (t < 64) {
      float c0p = fmaf(bfc[t], attn[Ww + t], bfc[t + 64] * attn[Ww + 64 + t]);
#pragma unroll
      for (int off = 32; off; off >>= 1) c0p += __shfl_xor(c0p, off);
      if (t == 0) cvs[Ww] = c0p;
    }
  }
  __syncthreads();
  if (t < Ww) {
    float s = 0.f;
#pragma unroll
    for (int j = 0; j < 8; ++j) s += sred[t + 128 * j];
    cvs[t] = s;
  }
  __syncthreads();

  // ---- P1: stream x[b]; 16 float4 loads issued upfront, then process ----
  // Thread (g, q2): rows w = g + 8k, cols [4*q2, 4*q2+4).
  float s1p[4] = {0.f, 0.f, 0.f, 0.f};
  float s2p[4] = {0.f, 0.f, 0.f, 0.f};
  {
    float4 L[16];
#pragma unroll
    for (int k = 0; k < 16; ++k)
      L[k] = *reinterpret_cast<const float4*>(xb + (size_t)(g + 8 * k) * Nn + 4 * q2);
#pragma unroll
    for (int k = 0; k < 16; ++k) {
      const int w = g + 8 * k;
      const float aw = attn[w];
      const float cw = cvs[w];
      const float4 v = L[k];
      s1p[0] = fmaf(v.x, aw, s1p[0]); s1p[1] = fmaf(v.y, aw, s1p[1]);
      s1p[2] = fmaf(v.z, aw, s1p[2]); s1p[3] = fmaf(v.w, aw, s1p[3]);
      s2p[0] = fmaf(v.x, cw, s2p[0]); s2p[1] = fmaf(v.y, cw, s2p[1]);
      s2p[2] = fmaf(v.z, cw, s2p[2]); s2p[3] = fmaf(v.w, cw, s2p[3]);
      uint2 pk;
      pk.x = pk_bf16(v.x, v.y);
      pk.y = pk_bf16(v.z, v.w);
      // tile[jg = q2>>1][w][(q2&1)*4 ..+4): cols n = 4*q2..+4
      *reinterpret_cast<uint2*>(tile + ((size_t)(q2 >> 1) * 129 + w) * 8 + (q2 & 1) * 4) = pk;
    }
  }

  // ---- P2: reduce s1/s2 over the 8 row-groups (two trips through sred) ----
  // Partial for col n from group g sits at sred[g*512 + n].
  *reinterpret_cast<f32x4*>(&sred[t * 4]) = (f32x4){s1p[0], s1p[1], s1p[2], s1p[3]};
  __syncthreads();
  float red = 0.f;
  if (t < 512) {
#pragma unroll
    for (int j = 0; j < 8; ++j) red += sred[j * 512 + t];
  }
  __syncthreads();   // all sred reads done before rewrite
  if (t < 512) s1s[t] = red * LOG2E;
  *reinterpret_cast<f32x4*>(&sred[t * 4]) = (f32x4){s2p[0], s2p[1], s2p[2], s2p[3]};
  __syncthreads();
  if (t < 512) {
    float d = 0.f;
#pragma unroll
    for (int j = 0; j < 8; ++j) d += sred[j * 512 + t];
    s2s[t] = (d + cvs[Ww]) * LOG2E;
  }
  __syncthreads();

  // ---- P4: MFMA loop; 16 waves x 16 rows; exp2; denominators via MFMA x ones ----
  const float s1i = s1s[i0 + wvw * 16 + wl];

  f32x4 acc[8];
  f32x4 accl = (f32x4){0.f, 0.f, 0.f, 0.f};
#pragma unroll
  for (int f = 0; f < 8; ++f) acc[f] = (f32x4){0.f, 0.f, 0.f, 0.f};
  short8 ones;
#pragma unroll
  for (int e = 0; e < 8; ++e) ones[e] = (short)0x3F80;  // bf16 1.0

  for (int jj = 0; jj < 16; ++jj) {
    const int jb = jj * 32 + 8 * lg;  // this lane's 8 consecutive j's
    float sv[8];
    *reinterpret_cast<float4*>(&sv[0]) = *reinterpret_cast<const float4*>(&s2s[jb]);
    *reinterpret_cast<float4*>(&sv[4]) = *reinterpret_cast<const float4*>(&s2s[jb + 4]);
    float p[8];
#pragma unroll
    for (int e = 0; e < 8; ++e) {
      const float u = s1i + sv[e];
      p[e] = v_exp2(fmaxf(u, ALPHA * u));   // no max subtraction (proven R9-R18)
    }
    short8 af;
    unsigned* au = reinterpret_cast<unsigned*>(&af);
    au[0] = pk_bf16(p[0], p[1]); au[1] = pk_bf16(p[2], p[3]);
    au[2] = pk_bf16(p[4], p[5]); au[3] = pk_bf16(p[6], p[7]);

    const ushort* tb = tile + (size_t)(jj * 4 + lg) * 129 * 8;
#pragma unroll
    for (int f = 0; f < 8; ++f) {
      const short8 bfr = *reinterpret_cast<const short8*>(tb + (16 * f + wl) * 8);
      acc[f] = __builtin_amdgcn_mfma_f32_16x16x32_bf16(af, bfr, acc[f], 0, 0, 0);
    }
    accl = __builtin_amdgcn_mfma_f32_16x16x32_bf16(af, ones, accl, 0, 0, 0);
  }

  // ---- P6: epilogue — sigmoid via exp2 + v_rcp (proven R18 form) ----
  float invl[4];
#pragma unroll
  for (int m = 0; m < 4; ++m) invl[m] = LOG2E * v_rcp(accl[m]);
  const int ibase = i0 + wvw * 16 + lg * 4;
  float* outb = out + (size_t)b * (Ww * Nn);
#pragma unroll
  for (int f = 0; f < 8; ++f) {
    float4 o;
    o.x = v_rcp(1.f + v_exp2(-(acc[f][0] * invl[0])));
    o.y = v_rcp(1.f + v_exp2(-(acc[f][1] * invl[1])));
    o.z = v_rcp(1.f + v_exp2(-(acc[f][2] * invl[2])));
    o.w = v_rcp(1.f + v_exp2(-(acc[f][3] * invl[3])));
    *reinterpret_cast<float4*>(outb + (16 * f + wl) * Nn + ibase) = o;
  }
}

extern "C" void kernel_launch(void* const* d_in, const int* in_sizes, int n_in,
                              void* d_out, int out_size, void* d_ws, size_t ws_size,
                              hipStream_t stream) {
  const float* x    = (const float*)d_in[0];  // (128,128,512)
  const float* Wfc  = (const float*)d_in[1];  // (128,128)
  const float* bfc  = (const float*)d_in[2];  // (128,)
  const float* attn = (const float*)d_in[3];  // (256,1)
  float* out = (float*)d_out;                 // (128,128,512)

  (void)hipFuncSetAttribute(reinterpret_cast<const void*>(&attn_k),
                            hipFuncAttributeMaxDynamicSharedMemorySize, SMEM12);
  attn_k<<<256, 1024, SMEM12, stream>>>(x, Wfc, bfc, attn, out);
}

// Round 20
// 25.931 us; speedup vs baseline: 1.1521x; 1.0172x over previous
//
#include <hip/hip_runtime.h>

#define Bb 128
#define Ww 128
#define Nn 512
#define ALPHA 0.2f
#define LOG2E 1.44269504088896340736f

typedef __attribute__((ext_vector_type(8))) short short8;
typedef __attribute__((ext_vector_type(4))) float f32x4;

// v_cvt_pk_bf16_f32: packs (lo,hi) -> u32 of 2 bf16 (RNE; proven R9-R19)
__device__ __forceinline__ unsigned pk_bf16(float lo, float hi) {
  unsigned r;
  asm("v_cvt_pk_bf16_f32 %0, %1, %2" : "=v"(r) : "v"(lo), "v"(hi));
  return r;
}

// v_exp_f32 computes 2^x on gfx950 (proven R13-R19)
__device__ __forceinline__ float v_exp2(float x) {
  float r;
  asm("v_exp_f32 %0, %1" : "=v"(r) : "v"(x));
  return r;
}

// v_rcp_f32: ~1ulp reciprocal (proven R18/R19)
__device__ __forceinline__ float v_rcp(float x) {
  float r;
  asm("v_rcp_f32 %0, %1" : "=v"(r) : "v"(x));
  return r;
}

// ---- dynamic LDS layout (bytes) ----
#define T_OFF   0
#define T_BYTES (64 * 129 * 8 * 2)     // ushort tile[64 jg][129 w][8] = 132096
#define SR_OFF  (T_OFF + T_BYTES)      // float sred[4096] = 16384
#define S1_OFF  (SR_OFF + 16384)       // float s1s[512]   = 2048
#define S2_OFF  (S1_OFF + 2048)        // float s2s[512]   = 2048
#define CV_OFF  (S2_OFF + 2048)        // float cvs[129]   (pad 528)
#define CP_OFF  (CV_OFF + 528)         // float cpart[1024] = 4096
#define SMEM13  (CP_OFF + 4096)        // 157200 < 163840

// One block = (batch b, i-half). 1024 threads = 16 waves = 4 waves/SIMD.
// R19 arithmetic EXACTLY (same FMA/reduce orders). Scheduling change only:
// Wfc issued oldest, x second -> cvec FMAs wait at vmcnt(16) and run UNDER the
// x fetch; s2 partials reuse the register-held x (no reload, no serial P0).
__launch_bounds__(1024, 1)
__global__ void attn_m(const float* __restrict__ x, const float* __restrict__ Wfc,
                       const float* __restrict__ bfc, const float* __restrict__ attn,
                       float* __restrict__ out) {
  extern __shared__ char smem[];
  ushort* tile  = (ushort*)(smem + T_OFF);
  float*  sred  = (float*)(smem + SR_OFF);
  float*  s1s   = (float*)(smem + S1_OFF);
  float*  s2s   = (float*)(smem + S2_OFF);
  float*  cvs   = (float*)(smem + CV_OFF);
  float*  cpart = (float*)(smem + CP_OFF);

  const int bid = blockIdx.x;
  const int xcd = bid & 7, idx = bid >> 3;
  const int b  = xcd * 16 + (idx >> 1);      // sibling i-half blocks share an XCD/L2
  const int i0 = (idx & 1) * 256;
  const int t  = threadIdx.x;                // 0..1023
  const int wvw = t >> 6;                    // wave 0..15
  const int lane = t & 63;
  const int wl = lane & 15, lg = lane >> 4;
  const int g  = t >> 7;                     // row-group 0..7 (wave-uniform)
  const int q2 = t & 127;                    // col-slice (4 floats)
  const float* xb = x + (size_t)b * (Ww * Nn);

  // ---- issue group 1 (oldest): Wfc column slice + c0 inputs ----
  float wreg[16];
#pragma unroll
  for (int vi = 0; vi < 16; ++vi)
    wreg[vi] = Wfc[(size_t)(g * 16 + vi) * Ww + q2];
  float c0p = 0.f;
  if (t < 64)
    c0p = fmaf(bfc[t], attn[Ww + t], bfc[t + 64] * attn[Ww + 64 + t]);
  __builtin_amdgcn_sched_barrier(0);   // pin: group 1 issued before x

  // ---- issue group 2: ALL 16 x float4 loads (rows g+8k, cols 4*q2) ----
  float4 L[16];
#pragma unroll
  for (int k = 0; k < 16; ++k)
    L[k] = *reinterpret_cast<const float4*>(xb + (size_t)(g + 8 * k) * Nn + 4 * q2);
  __builtin_amdgcn_sched_barrier(0);   // pin: x issued before wreg consumption

  // ---- cvec partials from wreg: waits vmcnt(16), x stays in flight ----
  {
    float cp = 0.f;
#pragma unroll
    for (int vi = 0; vi < 16; ++vi)
      cp = fmaf(attn[Ww + g * 16 + vi], wreg[vi], cp);   // attn[..] wave-uniform -> s_load
    cpart[t] = cp;                     // partial for col q2 from group g
    if (t < 64) {
      float cc = c0p;
#pragma unroll
      for (int off = 32; off; off >>= 1) cc += __shfl_xor(cc, off);
      if (t == 0) cvs[Ww] = cc;
    }
  }

  // ---- drain x: s1 partials + bf16 tile write (R19 order exactly) ----
  float s1p[4] = {0.f, 0.f, 0.f, 0.f};
#pragma unroll
  for (int k = 0; k < 16; ++k) {
    const int w = g + 8 * k;
    const float aw = attn[w];          // wave-uniform -> s_load
    const float4 v = L[k];
    s1p[0] = fmaf(v.x, aw, s1p[0]); s1p[1] = fmaf(v.y, aw, s1p[1]);
    s1p[2] = fmaf(v.z, aw, s1p[2]); s1p[3] = fmaf(v.w, aw, s1p[3]);
    uint2 pk;
    pk.x = pk_bf16(v.x, v.y);
    pk.y = pk_bf16(v.z, v.w);
    *reinterpret_cast<uint2*>(tile + ((size_t)(q2 >> 1) * 129 + w) * 8 + (q2 & 1) * 4) = pk;
  }
  *reinterpret_cast<f32x4*>(&sred[t * 4]) = (f32x4){s1p[0], s1p[1], s1p[2], s1p[3]};
  __syncthreads();                     // BAR1: cpart + sred(s1) + tile visible

  // ---- cvs reduce (t<128) + s1 reduce (t<512), same orders as R19 ----
  if (t < Ww) {
    float s = 0.f;
#pragma unroll
    for (int j = 0; j < 8; ++j) s += cpart[t + 128 * j];
    cvs[t] = s;
  }
  float red = 0.f;
  if (t < 512) {
#pragma unroll
    for (int j = 0; j < 8; ++j) red += sred[j * 512 + t];
  }
  __syncthreads();                     // BAR2: sred(s1) reads done; cvs visible
  if (t < 512) s1s[t] = red * LOG2E;

  // ---- s2 partials from the register-held x (no reload; R19 FMA order) ----
  float s2p[4] = {0.f, 0.f, 0.f, 0.f};
#pragma unroll
  for (int k = 0; k < 16; ++k) {
    const int w = g + 8 * k;
    const float cw = cvs[w];
    const float4 v = L[k];
    s2p[0] = fmaf(v.x, cw, s2p[0]); s2p[1] = fmaf(v.y, cw, s2p[1]);
    s2p[2] = fmaf(v.z, cw, s2p[2]); s2p[3] = fmaf(v.w, cw, s2p[3]);
  }
  *reinterpret_cast<f32x4*>(&sred[t * 4]) = (f32x4){s2p[0], s2p[1], s2p[2], s2p[3]};
  __syncthreads();                     // BAR3: sred(s2) visible
  if (t < 512) {
    float d = 0.f;
#pragma unroll
    for (int j = 0; j < 8; ++j) d += sred[j * 512 + t];
    s2s[t] = (d + cvs[Ww]) * LOG2E;
  }
  __syncthreads();                     // BAR4: s2s ready

  // ---- P4: MFMA loop (R19 verbatim) ----
  const float s1i = s1s[i0 + wvw * 16 + wl];

  f32x4 acc[8];
  f32x4 accl = (f32x4){0.f, 0.f, 0.f, 0.f};
#pragma unroll
  for (int f = 0; f < 8; ++f) acc[f] = (f32x4){0.f, 0.f, 0.f, 0.f};
  short8 ones;
#pragma unroll
  for (int e = 0; e < 8; ++e) ones[e] = (short)0x3F80;  // bf16 1.0

  for (int jj = 0; jj < 16; ++jj) {
    const int jb = jj * 32 + 8 * lg;  // this lane's 8 consecutive j's
    float sv[8];
    *reinterpret_cast<float4*>(&sv[0]) = *reinterpret_cast<const float4*>(&s2s[jb]);
    *reinterpret_cast<float4*>(&sv[4]) = *reinterpret_cast<const float4*>(&s2s[jb + 4]);
    float p[8];
#pragma unroll
    for (int e = 0; e < 8; ++e) {
      const float u = s1i + sv[e];
      p[e] = v_exp2(fmaxf(u, ALPHA * u));   // no max subtraction (proven R9-R19)
    }
    short8 af;
    unsigned* au = reinterpret_cast<unsigned*>(&af);
    au[0] = pk_bf16(p[0], p[1]); au[1] = pk_bf16(p[2], p[3]);
    au[2] = pk_bf16(p[4], p[5]); au[3] = pk_bf16(p[6], p[7]);

    const ushort* tb = tile + (size_t)(jj * 4 + lg) * 129 * 8;
#pragma unroll
    for (int f = 0; f < 8; ++f) {
      const short8 bfr = *reinterpret_cast<const short8*>(tb + (16 * f + wl) * 8);
      acc[f] = __builtin_amdgcn_mfma_f32_16x16x32_bf16(af, bfr, acc[f], 0, 0, 0);
    }
    accl = __builtin_amdgcn_mfma_f32_16x16x32_bf16(af, ones, accl, 0, 0, 0);
  }

  // ---- P6: epilogue (R19 verbatim) ----
  float invl[4];
#pragma unroll
  for (int m = 0; m < 4; ++m) invl[m] = LOG2E * v_rcp(accl[m]);
  const int ibase = i0 + wvw * 16 + lg * 4;
  float* outb = out + (size_t)b * (Ww * Nn);
#pragma unroll
  for (int f = 0; f < 8; ++f) {
    float4 o;
    o.x = v_rcp(1.f + v_exp2(-(acc[f][0] * invl[0])));
    o.y = v_rcp(1.f + v_exp2(-(acc[f][1] * invl[1])));
    o.z = v_rcp(1.f + v_exp2(-(acc[f][2] * invl[2])));
    o.w = v_rcp(1.f + v_exp2(-(acc[f][3] * invl[3])));
    *reinterpret_cast<float4*>(outb + (16 * f + wl) * Nn + ibase) = o;
  }
}

extern "C" void kernel_launch(void* const* d_in, const int* in_sizes, int n_in,
                              void* d_out, int out_size, void* d_ws, size_t ws_size,
                              hipStream_t stream) {
  const float* x    = (const float*)d_in[0];  // (128,128,512)
  const float* Wfc  = (const float*)d_in[1];  // (128,128)
  const float* bfc  = (const float*)d_in[2];  // (128,)
  const float* attn = (const float*)d_in[3];  // (256,1)
  float* out = (float*)d_out;                 // (128,128,512)

  (void)hipFuncSetAttribute(reinterpret_cast<const void*>(&attn_m),
                            hipFuncAttributeMaxDynamicSharedMemorySize, SMEM13);
  attn_m<<<256, 1024, SMEM13, stream>>>(x, Wfc, bfc, attn, out);
}